// Round 4
// baseline (1154.775 us; speedup 1.0000x reference)
//
#include <hip/hip_runtime.h>
#include <cstdint>
#include <cstddef>

#define NNODES 50000
#define NRELS  256
#define DIM    256
#define TT     24
#define EE     20000
#define BATCH  16
#define SEQQ   7

typedef __bf16 bf16;
typedef __bf16 bf16x4 __attribute__((ext_vector_type(4)));
typedef __bf16 bf16x8 __attribute__((ext_vector_type(8)));
typedef float  f32x4  __attribute__((ext_vector_type(4)));

// async global->LDS, 16B per lane; dest is wave-uniform base (+lane*16 by HW)
__device__ __forceinline__ void gload16(const void* g, void* l){
  __builtin_amdgcn_global_load_lds((const __attribute__((address_space(1))) void*)g,
                                   (__attribute__((address_space(3))) void*)l, 16, 0, 0);
}

// ---------------- prep kernels ----------------

// fp32 -> bf16, 8 elems/thread
__global__ void k_cvt8(const float* __restrict__ in, bf16* __restrict__ out, int n8){
  int i = blockIdx.x*256 + threadIdx.x;
  if (i >= n8) return;
  const float4* p = (const float4*)in + (size_t)i*2;
  float4 a = p[0], b = p[1];
  bf16x8 o;
  o[0]=(bf16)a.x; o[1]=(bf16)a.y; o[2]=(bf16)a.z; o[3]=(bf16)a.w;
  o[4]=(bf16)b.x; o[5]=(bf16)b.y; o[6]=(bf16)b.z; o[7]=(bf16)b.w;
  ((bf16x8*)out)[i] = o;
}

// Fused edge weight, transposed: WbT[n][k], k in [0,768).
__global__ void k_build_wbt(const float* __restrict__ tW, const float* __restrict__ eW,
                            bf16* __restrict__ WbT){
  int n = blockIdx.x, j = threadIdx.x;
  WbT[(size_t)n*768 + j]       = (bf16)eW[(size_t)j*256 + n];
  WbT[(size_t)n*768 + 512 + j] = (bf16)eW[(size_t)(512+j)*256 + n];
  float acc = 0.f;
  for (int m=0; m<256; ++m) acc += tW[(size_t)j*256 + m] * eW[(size_t)(256+m)*256 + n];
  WbT[(size_t)n*768 + 256 + j] = (bf16)acc;
}

// fused bias: bfused[n] = edge_w_b[n] + sum_m text_w_b[m]*W2[m][n]
__global__ void k_bias(const float* __restrict__ tb, const float* __restrict__ eW,
                       const float* __restrict__ eb, float* __restrict__ bf){
  int n = threadIdx.x;
  float acc = eb[n];
  for (int m=0; m<256; ++m) acc += tb[m] * eW[(size_t)(256+m)*256 + n];
  bf[n] = acc;
}

// gru weight [256][768] -> transposed bf16 [768][256]
__global__ void k_gruWT(const float* __restrict__ W, bf16* __restrict__ WT){
  int n = blockIdx.x, k = threadIdx.x;
  WT[(size_t)n*256 + k] = (bf16)W[(size_t)k*768 + n];
}

// per-t histogram of rels + exclusive scan -> counts/offs/cursor
__global__ void k_hist(const int* __restrict__ rel, int* __restrict__ counts,
                       int* __restrict__ offs, int* __restrict__ cursor){
  __shared__ int hist[256];
  __shared__ int scan[256];
  int t = blockIdx.x, tid = threadIdx.x;
  hist[tid] = 0;
  __syncthreads();
  for (int e = tid; e < EE; e += 256) atomicAdd(&hist[rel[(size_t)t*EE + e]], 1);
  __syncthreads();
  int v = hist[tid];
  scan[tid] = v;
  __syncthreads();
  for (int d=1; d<256; d<<=1){
    int add = (tid >= d) ? scan[tid-d] : 0;
    __syncthreads();
    scan[tid] += add;
    __syncthreads();
  }
  int ex = scan[tid] - v;
  counts[t*256+tid] = v;
  offs[t*256+tid]   = ex;
  cursor[t*256+tid] = ex;
}

// bucket edge ids by (t, rel); also pre-permute src/dst indices
__global__ void k_perm(const int* __restrict__ rel, const int* __restrict__ esrc,
                       const int* __restrict__ edst, int* __restrict__ cursor,
                       int* __restrict__ perm, int* __restrict__ src_p,
                       int* __restrict__ dst_p){
  int t = blockIdx.y;
  int e = blockIdx.x*256 + threadIdx.x;
  if (e < EE){
    int r = rel[(size_t)t*EE + e];
    int p = atomicAdd(&cursor[t*256 + r], 1);
    perm[(size_t)t*EE + p]  = e;
    src_p[(size_t)t*EE + p] = esrc[(size_t)t*EE + e];
    dst_p[(size_t)t*EE + p] = edst[(size_t)t*EE + e];
  }
}

// gather-permute-convert text rows: tp[t*EE+p] = bf16(text[t*EE+perm[t*EE+p]])
__global__ void k_textp(const float* __restrict__ text, const int* __restrict__ perm,
                        bf16* __restrict__ tp){
  int g = blockIdx.x*4 + (threadIdx.x >> 6);   // global sorted row
  int lane = threadIdx.x & 63;
  int t = g / EE;
  int e = perm[g];
  float4 v = ((const float4*)(text + ((size_t)t*EE + e)*256))[lane];
  bf16x4 o;
  o[0]=(bf16)v.x; o[1]=(bf16)v.y; o[2]=(bf16)v.z; o[3]=(bf16)v.w;
  ((bf16x4*)(tp + (size_t)g*256))[lane] = o;
}

// ---------------- edge GEMM + fused scatter-mean ----------------
// Grid (rel, t, nhalf). Block: M=96-row chunks x N=128 cols, K=768, BK=32.
// Counted-vmcnt 2-buffer pipeline (T4): per step, 4 global_load_lds per wave
// (uniform), raw s_barrier + asm s_waitcnt vmcnt(4) so next-step loads stay
// in flight across the barrier. Two raw barriers per step:
//   STAGE(ks+1,buf^1) ; vmcnt(4)+bar ; ds_read buf ; lgkmcnt(0)+bar ; MFMA
// Buffer overwrite (stage ks+2 at top of step ks+1) is always after barrier#2
// of step ks, which follows all reads of that buffer.
__global__ __launch_bounds__(256) void k_edge(
    const bf16* __restrict__ node_bf, const bf16* __restrict__ text_bp,
    const bf16* __restrict__ WbT, const float* __restrict__ bfused,
    const int* __restrict__ src_p, const int* __restrict__ dst_p,
    const int* __restrict__ counts, const int* __restrict__ offs,
    bf16* __restrict__ rel_bf)
{
  int r = blockIdx.x, t = blockIdx.y, nh = blockIdx.z;
  int tid = threadIdx.x;
  int lane = tid & 63, w = tid >> 6;
  int tr = t*256 + r;
  int nE = counts[tr];
  int n0 = nh*128;
  if (nE == 0){
    if (tid < 128) rel_bf[(size_t)tr*256 + n0 + tid] = (bf16)0.f;
    return;
  }
  __shared__ __align__(16) bf16 Alds[2][96*32];    // 12KB
  __shared__ __align__(16) bf16 Blds[2][128*32];   // 16KB
  __shared__ float colsum[128];
  __shared__ unsigned long long rowPtr[3][96];     // 2.25KB
  if (tid < 128) colsum[tid] = 0.f;
  int base = offs[tr];
  int cw = w*32;                                   // wave's local col base
  int l15 = lane & 15, lq = lane >> 4;
  float bias[2];
  #pragma unroll
  for (int ni=0; ni<2; ++ni) bias[ni] = bfused[n0 + cw + ni*16 + l15];

  int nchunks = (nE + 95)/96;
  for (int ch=0; ch<nchunks; ++ch){
    int row0 = ch*96;
    __syncthreads();
    if (tid < 96){
      int rr = base + row0 + tid;
      if (rr > EE-1) rr = EE-1;                    // padding rows: valid addr, masked later
      size_t g = (size_t)t*EE + rr;
      rowPtr[0][tid] = (unsigned long long)(node_bf + (size_t)src_p[g]*256);
      rowPtr[1][tid] = (unsigned long long)(text_bp + g*256);
      rowPtr[2][tid] = (unsigned long long)(node_bf + (size_t)dst_p[g]*256);
    }
    __syncthreads();
    int mrows = nE - row0; if (mrows > 96) mrows = 96;
    const int miCnt = (mrows + 15) >> 4;           // live 16-row frags (block-uniform)

    // STAGE(kn, bi): exactly 4 global_load_lds per wave, all waves, always.
    auto STAGE = [&](int kn, int bi){
      int reg = kn >> 3;                           // 0 src / 1 text / 2 dst
      int kb  = (kn & 7) * 64;                     // byte offset within row
      { // A pass0: chunks 0..255 (rows 0..63)
        int c = tid;
        int rowA = c >> 2, part = c & 3;
        int pp = part ^ ((rowA>>1)&3);
        const char* src = (const char*)rowPtr[reg][rowA] + kb + pp*16;
        gload16(src, (char*)&Alds[bi][0] + (size_t)(w*64)*16);
      }
      if (w < 2){ // A pass1: chunks 256..383 (rows 64..95), waves 0,1
        int c = 256 + w*64 + lane;
        int rowA = c >> 2, part = c & 3;
        int pp = part ^ ((rowA>>1)&3);
        const char* src = (const char*)rowPtr[reg][rowA] + kb + pp*16;
        gload16(src, (char*)&Alds[bi][0] + (size_t)(256 + w*64)*16);
      } else {    // waves 2,3: re-issue their B pass0 chunk (same src+dest,
                  // same bytes) purely to keep the per-wave vmcnt count uniform
        int c = tid;
        int nn = c >> 2, part = c & 3;
        int pp = part ^ ((nn>>1)&3);
        const char* src = (const char*)(WbT + (size_t)(n0+nn)*768 + kn*32) + pp*16;
        gload16(src, (char*)&Blds[bi][0] + (size_t)(w*64)*16);
      }
      // B: 128 cols x 32 k = 512 chunks, 2 passes
      #pragma unroll
      for (int p=0;p<2;++p){
        int c = p*256 + tid;
        int nn = c >> 2, part = c & 3;
        int pp = part ^ ((nn>>1)&3);
        const char* src = (const char*)(WbT + (size_t)(n0+nn)*768 + kn*32) + pp*16;
        gload16(src, (char*)&Blds[bi][0] + (size_t)(p*256 + w*64)*16);
      }
    };

    f32x4 acc[6][2];
    f32x4 z4 = {0.f,0.f,0.f,0.f};
    #pragma unroll
    for (int mi=0;mi<6;++mi)
      #pragma unroll
      for (int ni=0;ni<2;++ni) acc[mi][ni] = z4;

    STAGE(0, 0);

    for (int ks=0; ks<24; ++ks){
      int bi = ks & 1;
      if (ks < 23){
        STAGE(ks+1, bi^1);
        // wait only for stage(ks): stage(ks+1)'s 4 loads remain in flight
        asm volatile("s_waitcnt vmcnt(4)\n\ts_barrier" ::: "memory");
      } else {
        asm volatile("s_waitcnt vmcnt(0)\n\ts_barrier" ::: "memory");
      }
      __builtin_amdgcn_sched_barrier(0);
      bf16x8 a[6], b[2];
      #pragma unroll
      for (int ni=0;ni<2;++ni){
        int nn = cw + ni*16 + l15;
        b[ni] = *(const bf16x8*)((const char*)&Blds[bi][0]
                 + (size_t)nn*64 + (size_t)((lq ^ ((nn>>1)&3))*16));
      }
      #pragma unroll
      for (int mi=0;mi<6;++mi){
        if (mi < miCnt){
          int rowA = mi*16 + l15;
          a[mi] = *(const bf16x8*)((const char*)&Alds[bi][0]
                   + (size_t)rowA*64 + (size_t)((lq ^ ((rowA>>1)&3))*16));
        }
      }
      // all reads of buf[bi] done before barrier#2 -> safe to overwrite next step
      asm volatile("s_waitcnt lgkmcnt(0)\n\ts_barrier" ::: "memory");
      __builtin_amdgcn_sched_barrier(0);
      #pragma unroll
      for (int mi=0;mi<6;++mi){
        if (mi < miCnt){
          #pragma unroll
          for (int ni=0;ni<2;++ni)
            acc[mi][ni] = __builtin_amdgcn_mfma_f32_16x16x32_bf16(a[mi], b[ni], acc[mi][ni], 0, 0, 0);
        }
      }
    }

    // epilogue: bias + relu + masked column reduce into LDS colsum
    #pragma unroll
    for (int ni=0;ni<2;++ni){
      float s = 0.f;
      #pragma unroll
      for (int mi=0;mi<6;++mi){
        if (mi < miCnt){
          #pragma unroll
          for (int q=0;q<4;++q){
            int rloc = mi*16 + lq*4 + q;
            if (row0 + rloc < nE){
              float v = acc[mi][ni][q] + bias[ni];
              s += fmaxf(v, 0.f);
            }
          }
        }
      }
      atomicAdd(&colsum[cw + ni*16 + l15], s);
    }
  }
  __syncthreads();
  if (tid < 128)
    rel_bf[(size_t)tr*256 + n0 + tid] = (bf16)(colsum[tid] / (float)nE);
}

// ---------------- plain bf16 GEMM, K=256 fixed, N stride 768, + bias ----------------
__global__ __launch_bounds__(256) void k_gemm(
    const bf16* __restrict__ A, const bf16* __restrict__ BT,
    const float* __restrict__ bias, float* __restrict__ Out)
{
  int m0 = blockIdx.x*128, n0 = blockIdx.y*128;
  int tid = threadIdx.x, lane = tid&63, w = tid>>6;
  int l15 = lane&15, lq = lane>>4;
  __shared__ __align__(16) bf16 Al[128*32];
  __shared__ __align__(16) bf16 Bl[128*32];
  int wr = (w&1)*64, wc = (w>>1)*64;
  f32x4 acc[4][4];
  f32x4 z4 = {0.f,0.f,0.f,0.f};
  #pragma unroll
  for (int mi=0;mi<4;++mi)
    #pragma unroll
    for (int ni=0;ni<4;++ni) acc[mi][ni]=z4;
  for (int ks=0; ks<8; ++ks){
    int k0 = ks*32;
    #pragma unroll
    for (int p=0;p<2;++p){
      int c = p*256 + tid;
      int rw = c>>2, part = c&3;
      int pp = part ^ ((rw>>1)&3);
      const char* src = (const char*)(A + (size_t)(m0+rw)*256 + k0) + pp*16;
      gload16(src, (char*)Al + (size_t)(p*256 + w*64)*16);
    }
    #pragma unroll
    for (int p=0;p<2;++p){
      int c = p*256 + tid;
      int nn = c>>2, part = c&3;
      int pp = part ^ ((nn>>1)&3);
      const char* src = (const char*)(BT + (size_t)(n0+nn)*256 + k0) + pp*16;
      gload16(src, (char*)Bl + (size_t)(p*256 + w*64)*16);
    }
    __syncthreads();
    bf16x8 a[4], b[4];
    #pragma unroll
    for (int mi=0;mi<4;++mi){
      int rw = wr + mi*16 + l15;
      a[mi] = *(const bf16x8*)((const char*)Al + (size_t)rw*64 + (size_t)((lq ^ ((rw>>1)&3))*16));
    }
    #pragma unroll
    for (int ni=0;ni<4;++ni){
      int nn = wc + ni*16 + l15;
      b[ni] = *(const bf16x8*)((const char*)Bl + (size_t)nn*64 + (size_t)((lq ^ ((nn>>1)&3))*16));
    }
    #pragma unroll
    for (int mi=0;mi<4;++mi)
      #pragma unroll
      for (int ni=0;ni<4;++ni)
        acc[mi][ni] = __builtin_amdgcn_mfma_f32_16x16x32_bf16(a[mi], b[ni], acc[mi][ni], 0,0,0);
    __syncthreads();
  }
  #pragma unroll
  for (int ni=0;ni<4;++ni){
    int col = n0 + wc + ni*16 + l15;
    float bv = bias[col];
    #pragma unroll
    for (int mi=0;mi<4;++mi){
      #pragma unroll
      for (int q=0;q<4;++q){
        int row = m0 + wr + mi*16 + lq*4 + q;
        Out[(size_t)row*768 + col] = acc[mi][ni][q] + bv;
      }
    }
  }
}

// ---------------- GRU elementwise update ----------------
__global__ void k_update(const float* __restrict__ GI, const float* __restrict__ gh,
                         const float* __restrict__ bhh, const int* __restrict__ time_idx,
                         const float* __restrict__ h_in, float* __restrict__ h_out,
                         bf16* __restrict__ hbf_out, float* __restrict__ out_final, int s)
{
  int row = blockIdx.x;           // b*256 + r
  int d = threadIdx.x;
  int b = row >> 8, rr = row & 255;
  int t = time_idx[b*SEQQ + s];
  size_t gib = (size_t)(t*256 + rr)*768;
  float ir = GI[gib + d], iz = GI[gib + 256 + d], inn = GI[gib + 512 + d];
  float hr, hz, hn;
  if (s == 0){ hr = bhh[d]; hz = bhh[256+d]; hn = bhh[512+d]; }
  else { size_t gb = (size_t)row*768; hr = gh[gb+d]; hz = gh[gb+256+d]; hn = gh[gb+512+d]; }
  float rg = 1.f/(1.f + __expf(-(ir+hr)));
  float zz = 1.f/(1.f + __expf(-(iz+hz)));
  float nn = tanhf(inn + rg*hn);
  float hp = (s==0) ? 0.f : h_in[(size_t)row*256 + d];
  float hv = (1.f - zz)*nn + zz*hp;
  if (s == SEQQ-1){
    out_final[(size_t)row*256 + d] = hv;
  } else {
    h_out[(size_t)row*256 + d] = hv;
    hbf_out[(size_t)row*256 + d] = (bf16)hv;
  }
}

// ---------------- launch ----------------
extern "C" void kernel_launch(void* const* d_in, const int* in_sizes, int n_in,
                              void* d_out, int out_size, void* d_ws, size_t ws_size,
                              hipStream_t stream)
{
  (void)in_sizes; (void)n_in; (void)out_size; (void)ws_size;
  const float* node_embeds = (const float*)d_in[0];
  const float* text_emb    = (const float*)d_in[1];
  const float* text_w_W    = (const float*)d_in[2];
  const float* text_w_b    = (const float*)d_in[3];
  const float* edge_w_W    = (const float*)d_in[4];
  const float* edge_w_b    = (const float*)d_in[5];
  const float* gru_Wih     = (const float*)d_in[6];
  const float* gru_Whh     = (const float*)d_in[7];
  const float* gru_bih     = (const float*)d_in[8];
  const float* gru_bhh     = (const float*)d_in[9];
  const int* edge_src      = (const int*)d_in[10];
  const int* edge_dst      = (const int*)d_in[11];
  const int* edge_rel      = (const int*)d_in[12];
  const int* time_idx      = (const int*)d_in[13];
  float* out = (float*)d_out;
  char* ws = (char*)d_ws;

  size_t o = 0;
  bf16*  WbT    = (bf16*) (ws + o); o += (size_t)768*256*2;
  bf16*  WihT   = (bf16*) (ws + o); o += (size_t)768*256*2;
  bf16*  WhhT   = (bf16*) (ws + o); o += (size_t)768*256*2;
  float* bfused = (float*)(ws + o); o += 1024;
  bf16*  node_bf= (bf16*) (ws + o); o += (size_t)NNODES*256*2;
  int*   counts = (int*)  (ws + o); o += (size_t)TT*256*4;
  int*   offs   = (int*)  (ws + o); o += (size_t)TT*256*4;
  int*   cursor = (int*)  (ws + o); o += (size_t)TT*256*4;
  int*   perm   = (int*)  (ws + o); o += (size_t)TT*EE*4;
  int*   src_p  = (int*)  (ws + o); o += (size_t)TT*EE*4;
  int*   dst_p  = (int*)  (ws + o); o += (size_t)TT*EE*4;
  bf16*  rel_bf = (bf16*) (ws + o); o += (size_t)TT*256*256*2;
  float* GI     = (float*)(ws + o); o += (size_t)TT*256*768*4;
  float* h      = (float*)(ws + o); o += (size_t)4096*256*4;
  bf16*  hbf    = (bf16*) (ws + o); o += (size_t)4096*256*2;
  float* gh     = (float*)(ws + o); o += (size_t)4096*768*4;
  bf16*  text_bp= (bf16*) (ws + o); o += (size_t)TT*EE*256*2;   // same layout as r3 (fit proven)

  k_cvt8<<<6250,256,0,stream>>>(node_embeds, node_bf, NNODES*256/8);
  k_build_wbt<<<256,256,0,stream>>>(text_w_W, edge_w_W, WbT);
  k_bias<<<1,256,0,stream>>>(text_w_b, edge_w_W, edge_w_b, bfused);
  k_gruWT<<<768,256,0,stream>>>(gru_Wih, WihT);
  k_gruWT<<<768,256,0,stream>>>(gru_Whh, WhhT);
  k_hist<<<TT,256,0,stream>>>(edge_rel, counts, offs, cursor);
  k_perm<<<dim3((EE+255)/256,TT),256,0,stream>>>(edge_rel, edge_src, edge_dst,
                                                 cursor, perm, src_p, dst_p);
  k_textp<<<TT*EE/4,256,0,stream>>>(text_emb, perm, text_bp);
  k_edge<<<dim3(256,TT,2),256,0,stream>>>(node_bf, text_bp, WbT, bfused,
                                          src_p, dst_p, counts, offs, rel_bf);
  k_gemm<<<dim3(48,6),256,0,stream>>>(rel_bf, WihT, gru_bih, GI);
  for (int s=0; s<SEQQ; ++s){
    if (s > 0)
      k_gemm<<<dim3(32,6),256,0,stream>>>(hbf, WhhT, gru_bhh, gh);
    k_update<<<4096,256,0,stream>>>(GI, gh, gru_bhh, time_idx, h, h, hbf, out, s);
  }
}

// Round 5
// 671.142 us; speedup vs baseline: 1.7206x; 1.7206x over previous
//
#include <hip/hip_runtime.h>
#include <cstdint>
#include <cstddef>

#define NNODES 50000
#define NPAD   50048        // 391*128, padded M for P/Q GEMM
#define NRELS  256
#define DIM    256
#define TT     24
#define EE     20000
#define BATCH  16
#define SEQQ   7

typedef __bf16 bf16;
typedef __bf16 bf16x8 __attribute__((ext_vector_type(8)));
typedef float  f32x4  __attribute__((ext_vector_type(4)));

// async global->LDS, 16B per lane; dest is wave-uniform base (+lane*16 by HW)
__device__ __forceinline__ void gload16(const void* g, void* l){
  __builtin_amdgcn_global_load_lds((const __attribute__((address_space(1))) void*)g,
                                   (__attribute__((address_space(3))) void*)l, 16, 0, 0);
}

// ---------------- prep kernels ----------------

// fp32 -> bf16, 8 elems/thread
__global__ void k_cvt8(const float* __restrict__ in, bf16* __restrict__ out, int n8){
  int i = blockIdx.x*256 + threadIdx.x;
  if (i >= n8) return;
  const float4* p = (const float4*)in + (size_t)i*2;
  float4 a = p[0], b = p[1];
  bf16x8 o;
  o[0]=(bf16)a.x; o[1]=(bf16)a.y; o[2]=(bf16)a.z; o[3]=(bf16)a.w;
  o[4]=(bf16)b.x; o[5]=(bf16)b.y; o[6]=(bf16)b.z; o[7]=(bf16)b.w;
  ((bf16x8*)out)[i] = o;
}

// Fused edge weight, transposed: WbT[n][k], k in [0,768) = [W1 | W2fold | W3].
__global__ void k_build_wbt(const float* __restrict__ tW, const float* __restrict__ eW,
                            bf16* __restrict__ WbT){
  int n = blockIdx.x, j = threadIdx.x;
  WbT[(size_t)n*768 + j]       = (bf16)eW[(size_t)j*256 + n];
  WbT[(size_t)n*768 + 512 + j] = (bf16)eW[(size_t)(512+j)*256 + n];
  float acc = 0.f;
  for (int m=0; m<256; ++m) acc += tW[(size_t)j*256 + m] * eW[(size_t)(256+m)*256 + n];
  WbT[(size_t)n*768 + 256 + j] = (bf16)acc;
}

// fused bias: bfused[n] = edge_w_b[n] + sum_m text_w_b[m]*W2[m][n]
__global__ void k_bias(const float* __restrict__ tb, const float* __restrict__ eW,
                       const float* __restrict__ eb, float* __restrict__ bf){
  int n = threadIdx.x;
  float acc = eb[n];
  for (int m=0; m<256; ++m) acc += tb[m] * eW[(size_t)(256+m)*256 + n];
  bf[n] = acc;
}

// gru weight [256][768] -> transposed bf16 [768][256]
__global__ void k_gruWT(const float* __restrict__ W, bf16* __restrict__ WT){
  int n = blockIdx.x, k = threadIdx.x;
  WT[(size_t)n*256 + k] = (bf16)W[(size_t)k*768 + n];
}

// per-t histogram of rels + exclusive scan -> counts/offs/cursor
__global__ void k_hist(const int* __restrict__ rel, int* __restrict__ counts,
                       int* __restrict__ offs, int* __restrict__ cursor){
  __shared__ int hist[256];
  __shared__ int scan[256];
  int t = blockIdx.x, tid = threadIdx.x;
  hist[tid] = 0;
  __syncthreads();
  for (int e = tid; e < EE; e += 256) atomicAdd(&hist[rel[(size_t)t*EE + e]], 1);
  __syncthreads();
  int v = hist[tid];
  scan[tid] = v;
  __syncthreads();
  for (int d=1; d<256; d<<=1){
    int add = (tid >= d) ? scan[tid-d] : 0;
    __syncthreads();
    scan[tid] += add;
    __syncthreads();
  }
  int ex = scan[tid] - v;
  counts[t*256+tid] = v;
  offs[t*256+tid]   = ex;
  cursor[t*256+tid] = ex;
}

// bucket edge ids by (t, rel); also pre-permute src/dst indices
__global__ void k_perm(const int* __restrict__ rel, const int* __restrict__ esrc,
                       const int* __restrict__ edst, int* __restrict__ cursor,
                       int* __restrict__ perm, int* __restrict__ src_p,
                       int* __restrict__ dst_p){
  int t = blockIdx.y;
  int e = blockIdx.x*256 + threadIdx.x;
  if (e < EE){
    int r = rel[(size_t)t*EE + e];
    int p = atomicAdd(&cursor[t*256 + r], 1);
    perm[(size_t)t*EE + p]  = e;
    src_p[(size_t)t*EE + p] = esrc[(size_t)t*EE + e];
    dst_p[(size_t)t*EE + p] = edst[(size_t)t*EE + e];
  }
}

// ---------------- projection GEMM ----------------
// Out[m][n] = A[m][:] @ WbT[n][koff:koff+256] (+bias), out bf16 stride 256.
// Tile M=128 x N=256, 4 waves each own 64 cols x all 128 rows (acc[8][4]).
// TEXTMODE=0: A = bf16 rows m0+r (node table), staged via global_load_lds.
// TEXTMODE=1: A = fp32 text rows gathered via perm (sorted order), reg-staged
//             with fp32->bf16 cvt; per-thread row pointers fixed per tile.
template<int TEXTMODE>
__global__ __launch_bounds__(256) void k_proj(
    const bf16* __restrict__ Abf, const float* __restrict__ Afp,
    const int* __restrict__ perm, const bf16* __restrict__ WbT, int koff,
    const float* __restrict__ bias, bf16* __restrict__ out)
{
  int m0 = blockIdx.x*128;
  int tid = threadIdx.x, lane = tid&63, w = tid>>6;
  int l15 = lane&15, lq = lane>>4;
  int c0 = w*64;
  __shared__ __align__(16) bf16 Al[128*32];   // 8KB
  __shared__ __align__(16) bf16 Bl[256*32];   // 16KB

  // per-thread fixed A staging rows (chunks tid and 256+tid)
  int r0 = tid>>2, r1 = 64 + (tid>>2);
  int part = tid&3;
  int pp0 = part ^ ((r0>>1)&3);               // same swizzle for r1 (r1>>1 = 32+(r0>>1))
  const float* aP0 = nullptr; const float* aP1 = nullptr;
  if (TEXTMODE){
    size_t g0 = (size_t)m0 + r0;  int t0 = (int)(g0/EE);
    size_t g1 = (size_t)m0 + r1;  int t1 = (int)(g1/EE);
    aP0 = Afp + ((size_t)t0*EE + perm[g0])*256;
    aP1 = Afp + ((size_t)t1*EE + perm[g1])*256;
  }
  float bias4[4];
  if (TEXTMODE){
    #pragma unroll
    for (int ni=0;ni<4;++ni) bias4[ni] = bias[c0 + ni*16 + l15];
  }

  f32x4 acc[8][4];
  f32x4 z4 = {0.f,0.f,0.f,0.f};
  #pragma unroll
  for (int mi=0;mi<8;++mi)
    #pragma unroll
    for (int ni=0;ni<4;++ni) acc[mi][ni]=z4;

  for (int ks=0; ks<8; ++ks){
    int k0 = ks*32;
    // ---- stage A ----
    if (TEXTMODE){
      {
        const float* sp = aP0 + k0 + pp0*8;
        float4 u = ((const float4*)sp)[0], v = ((const float4*)sp)[1];
        bf16x8 o;
        o[0]=(bf16)u.x; o[1]=(bf16)u.y; o[2]=(bf16)u.z; o[3]=(bf16)u.w;
        o[4]=(bf16)v.x; o[5]=(bf16)v.y; o[6]=(bf16)v.z; o[7]=(bf16)v.w;
        *(bf16x8*)((char*)Al + (size_t)tid*16) = o;
      }
      {
        const float* sp = aP1 + k0 + pp0*8;
        float4 u = ((const float4*)sp)[0], v = ((const float4*)sp)[1];
        bf16x8 o;
        o[0]=(bf16)u.x; o[1]=(bf16)u.y; o[2]=(bf16)u.z; o[3]=(bf16)u.w;
        o[4]=(bf16)v.x; o[5]=(bf16)v.y; o[6]=(bf16)v.z; o[7]=(bf16)v.w;
        *(bf16x8*)((char*)Al + (size_t)(256+tid)*16) = o;
      }
    } else {
      #pragma unroll
      for (int p=0;p<2;++p){
        int c = p*256 + tid;
        int rw = c>>2, prt = c&3;
        int pp = prt ^ ((rw>>1)&3);
        const char* src = (const char*)(Abf + (size_t)(m0+rw)*256 + k0) + pp*16;
        gload16(src, (char*)Al + (size_t)(p*256 + w*64)*16);
      }
    }
    // ---- stage B (256 cols x 32 k = 1024 chunks, 4 passes) ----
    #pragma unroll
    for (int p=0;p<4;++p){
      int c = p*256 + tid;
      int nn = c>>2, prt = c&3;
      int pp = prt ^ ((nn>>1)&3);
      const char* src = (const char*)(WbT + (size_t)nn*768 + koff + k0) + pp*16;
      gload16(src, (char*)Bl + (size_t)(p*256 + w*64)*16);
    }
    __syncthreads();
    bf16x8 a[8], b[4];
    #pragma unroll
    for (int ni=0;ni<4;++ni){
      int nn = c0 + ni*16 + l15;
      b[ni] = *(const bf16x8*)((const char*)Bl + (size_t)nn*64 + (size_t)((lq ^ ((nn>>1)&3))*16));
    }
    #pragma unroll
    for (int mi=0;mi<8;++mi){
      int rw = mi*16 + l15;
      a[mi] = *(const bf16x8*)((const char*)Al + (size_t)rw*64 + (size_t)((lq ^ ((rw>>1)&3))*16));
    }
    #pragma unroll
    for (int mi=0;mi<8;++mi)
      #pragma unroll
      for (int ni=0;ni<4;++ni)
        acc[mi][ni] = __builtin_amdgcn_mfma_f32_16x16x32_bf16(a[mi], b[ni], acc[mi][ni], 0,0,0);
    __syncthreads();
  }
  #pragma unroll
  for (int ni=0;ni<4;++ni){
    int col = c0 + ni*16 + l15;
    #pragma unroll
    for (int mi=0;mi<8;++mi){
      #pragma unroll
      for (int q=0;q<4;++q){
        int row = m0 + mi*16 + lq*4 + q;
        float v = acc[mi][ni][q];
        if (TEXTMODE) v += bias4[ni];
        out[(size_t)row*256 + col] = (bf16)v;
      }
    }
  }
}

// ---------------- combine: gather P/Q/T + relu + segment mean ----------------
// One block per (t,rel). 8 edge slots x 32 col-threads (8 cols each).
// No barriers in the loop; fp32 per-thread accumulators; one LDS reduce.
__global__ __launch_bounds__(256) void k_comb(
    const bf16* __restrict__ P, const bf16* __restrict__ Q,
    const bf16* __restrict__ T, const int* __restrict__ src_p,
    const int* __restrict__ dst_p, const int* __restrict__ counts,
    const int* __restrict__ offs, bf16* __restrict__ rel_bf)
{
  int r = blockIdx.x, t = blockIdx.y;
  int tid = threadIdx.x;
  int tr = t*256 + r;
  int nE = counts[tr];
  if (nE == 0){
    rel_bf[(size_t)tr*256 + tid] = (bf16)0.f;
    return;
  }
  int base = offs[tr];
  int es = tid>>5, cg = (tid&31)*8;
  float acc[8];
  #pragma unroll
  for (int j=0;j<8;++j) acc[j]=0.f;
  for (int i = es; i < nE; i += 8){
    size_t g = (size_t)t*EE + base + i;
    int s = src_p[g], d = dst_p[g];
    bf16x8 pv = *(const bf16x8*)(P + (size_t)s*256 + cg);
    bf16x8 qv = *(const bf16x8*)(Q + (size_t)d*256 + cg);
    bf16x8 tv = *(const bf16x8*)(T + g*256 + cg);
    #pragma unroll
    for (int j=0;j<8;++j)
      acc[j] += fmaxf((float)pv[j] + (float)qv[j] + (float)tv[j], 0.f);
  }
  __shared__ float red[8][256];
  #pragma unroll
  for (int j=0;j<8;++j) red[es][cg+j] = acc[j];
  __syncthreads();
  float s = 0.f;
  #pragma unroll
  for (int e=0;e<8;++e) s += red[e][tid];
  rel_bf[(size_t)tr*256 + tid] = (bf16)(s / (float)nE);
}

// ---------------- plain bf16 GEMM, K=256, BT stride 256, out f32 stride 768 ----------------
__global__ __launch_bounds__(256) void k_gemm(
    const bf16* __restrict__ A, const bf16* __restrict__ BT,
    const float* __restrict__ bias, float* __restrict__ Out)
{
  int m0 = blockIdx.x*128, n0 = blockIdx.y*128;
  int tid = threadIdx.x, lane = tid&63, w = tid>>6;
  int l15 = lane&15, lq = lane>>4;
  __shared__ __align__(16) bf16 Al[128*32];
  __shared__ __align__(16) bf16 Bl[128*32];
  int wr = (w&1)*64, wc = (w>>1)*64;
  f32x4 acc[4][4];
  f32x4 z4 = {0.f,0.f,0.f,0.f};
  #pragma unroll
  for (int mi=0;mi<4;++mi)
    #pragma unroll
    for (int ni=0;ni<4;++ni) acc[mi][ni]=z4;
  for (int ks=0; ks<8; ++ks){
    int k0 = ks*32;
    #pragma unroll
    for (int p=0;p<2;++p){
      int c = p*256 + tid;
      int rw = c>>2, part = c&3;
      int pp = part ^ ((rw>>1)&3);
      const char* src = (const char*)(A + (size_t)(m0+rw)*256 + k0) + pp*16;
      gload16(src, (char*)Al + (size_t)(p*256 + w*64)*16);
    }
    #pragma unroll
    for (int p=0;p<2;++p){
      int c = p*256 + tid;
      int nn = c>>2, part = c&3;
      int pp = part ^ ((nn>>1)&3);
      const char* src = (const char*)(BT + (size_t)(n0+nn)*256 + k0) + pp*16;
      gload16(src, (char*)Bl + (size_t)(p*256 + w*64)*16);
    }
    __syncthreads();
    bf16x8 a[4], b[4];
    #pragma unroll
    for (int mi=0;mi<4;++mi){
      int rw = wr + mi*16 + l15;
      a[mi] = *(const bf16x8*)((const char*)Al + (size_t)rw*64 + (size_t)((lq ^ ((rw>>1)&3))*16));
    }
    #pragma unroll
    for (int ni=0;ni<4;++ni){
      int nn = wc + ni*16 + l15;
      b[ni] = *(const bf16x8*)((const char*)Bl + (size_t)nn*64 + (size_t)((lq ^ ((nn>>1)&3))*16));
    }
    #pragma unroll
    for (int mi=0;mi<4;++mi)
      #pragma unroll
      for (int ni=0;ni<4;++ni)
        acc[mi][ni] = __builtin_amdgcn_mfma_f32_16x16x32_bf16(a[mi], b[ni], acc[mi][ni], 0,0,0);
    __syncthreads();
  }
  #pragma unroll
  for (int ni=0;ni<4;++ni){
    int col = n0 + wc + ni*16 + l15;
    float bv = bias[col];
    #pragma unroll
    for (int mi=0;mi<4;++mi){
      #pragma unroll
      for (int q=0;q<4;++q){
        int row = m0 + wr + mi*16 + lq*4 + q;
        Out[(size_t)row*768 + col] = acc[mi][ni][q] + bv;
      }
    }
  }
}

// ---------------- GRU elementwise update ----------------
__global__ void k_update(const float* __restrict__ GI, const float* __restrict__ gh,
                         const float* __restrict__ bhh, const int* __restrict__ time_idx,
                         const float* __restrict__ h_in, float* __restrict__ h_out,
                         bf16* __restrict__ hbf_out, float* __restrict__ out_final, int s)
{
  int row = blockIdx.x;           // b*256 + r
  int d = threadIdx.x;
  int b = row >> 8, rr = row & 255;
  int t = time_idx[b*SEQQ + s];
  size_t gib = (size_t)(t*256 + rr)*768;
  float ir = GI[gib + d], iz = GI[gib + 256 + d], inn = GI[gib + 512 + d];
  float hr, hz, hn;
  if (s == 0){ hr = bhh[d]; hz = bhh[256+d]; hn = bhh[512+d]; }
  else { size_t gb = (size_t)row*768; hr = gh[gb+d]; hz = gh[gb+256+d]; hn = gh[gb+512+d]; }
  float rg = 1.f/(1.f + __expf(-(ir+hr)));
  float zz = 1.f/(1.f + __expf(-(iz+hz)));
  float nn = tanhf(inn + rg*hn);
  float hp = (s==0) ? 0.f : h_in[(size_t)row*256 + d];
  float hv = (1.f - zz)*nn + zz*hp;
  if (s == SEQQ-1){
    out_final[(size_t)row*256 + d] = hv;
  } else {
    h_out[(size_t)row*256 + d] = hv;
    hbf_out[(size_t)row*256 + d] = (bf16)hv;
  }
}

// ---------------- launch ----------------
extern "C" void kernel_launch(void* const* d_in, const int* in_sizes, int n_in,
                              void* d_out, int out_size, void* d_ws, size_t ws_size,
                              hipStream_t stream)
{
  (void)in_sizes; (void)n_in; (void)out_size; (void)ws_size;
  const float* node_embeds = (const float*)d_in[0];
  const float* text_emb    = (const float*)d_in[1];
  const float* text_w_W    = (const float*)d_in[2];
  const float* text_w_b    = (const float*)d_in[3];
  const float* edge_w_W    = (const float*)d_in[4];
  const float* edge_w_b    = (const float*)d_in[5];
  const float* gru_Wih     = (const float*)d_in[6];
  const float* gru_Whh     = (const float*)d_in[7];
  const float* gru_bih     = (const float*)d_in[8];
  const float* gru_bhh     = (const float*)d_in[9];
  const int* edge_src      = (const int*)d_in[10];
  const int* edge_dst      = (const int*)d_in[11];
  const int* edge_rel      = (const int*)d_in[12];
  const int* time_idx      = (const int*)d_in[13];
  float* out = (float*)d_out;
  char* ws = (char*)d_ws;

  size_t o = 0;
  bf16*  WbT    = (bf16*) (ws + o); o += (size_t)768*256*2;
  bf16*  WihT   = (bf16*) (ws + o); o += (size_t)768*256*2;
  bf16*  WhhT   = (bf16*) (ws + o); o += (size_t)768*256*2;
  float* bfused = (float*)(ws + o); o += 1024;
  bf16*  node_bf= (bf16*) (ws + o); o += (size_t)NPAD*256*2;      // 25.6MB (padded)
  int*   counts = (int*)  (ws + o); o += (size_t)TT*256*4;
  int*   offs   = (int*)  (ws + o); o += (size_t)TT*256*4;
  int*   cursor = (int*)  (ws + o); o += (size_t)TT*256*4;
  int*   perm   = (int*)  (ws + o); o += (size_t)TT*EE*4;
  int*   src_p  = (int*)  (ws + o); o += (size_t)TT*EE*4;
  int*   dst_p  = (int*)  (ws + o); o += (size_t)TT*EE*4;
  bf16*  rel_bf = (bf16*) (ws + o); o += (size_t)TT*256*256*2;
  bf16*  P      = (bf16*) (ws + o); o += (size_t)NPAD*256*2;      // 25.6MB
  bf16*  Q      = (bf16*) (ws + o); o += (size_t)NPAD*256*2;      // 25.6MB
  // Tproj (245.8MB) aliases the GRU buffers: Tproj's last read (k_comb)
  // precedes the first GRU write (stream-ordered).
  size_t oT = o;
  bf16*  Tproj  = (bf16*) (ws + oT);
  float* GI     = (float*)(ws + oT); size_t o2 = oT + (size_t)TT*256*768*4;
  float* h      = (float*)(ws + o2); o2 += (size_t)4096*256*4;
  bf16*  hbf    = (bf16*) (ws + o2); o2 += (size_t)4096*256*2;
  float* gh     = (float*)(ws + o2); o2 += (size_t)4096*768*4;

  k_cvt8<<<6250,256,0,stream>>>(node_embeds, node_bf, NNODES*256/8);
  k_build_wbt<<<256,256,0,stream>>>(text_w_W, edge_w_W, WbT);
  k_bias<<<1,256,0,stream>>>(text_w_b, edge_w_W, edge_w_b, bfused);
  k_gruWT<<<768,256,0,stream>>>(gru_Wih, WihT);
  k_gruWT<<<768,256,0,stream>>>(gru_Whh, WhhT);
  k_hist<<<TT,256,0,stream>>>(edge_rel, counts, offs, cursor);
  k_perm<<<dim3((EE+255)/256,TT),256,0,stream>>>(edge_rel, edge_src, edge_dst,
                                                 cursor, perm, src_p, dst_p);
  // P = node@W1, Q = node@W3 (no bias); Tproj = gather(text,perm)@W2f + bfused
  k_proj<0><<<NPAD/128,256,0,stream>>>(node_bf, nullptr, nullptr, WbT, 0,   nullptr, P);
  k_proj<0><<<NPAD/128,256,0,stream>>>(node_bf, nullptr, nullptr, WbT, 512, nullptr, Q);
  k_proj<1><<<TT*EE/128,256,0,stream>>>(nullptr, text_emb, perm, WbT, 256, bfused, Tproj);
  k_comb<<<dim3(256,TT),256,0,stream>>>(P, Q, Tproj, src_p, dst_p, counts, offs, rel_bf);
  // GRU
  k_gemm<<<dim3(48,6),256,0,stream>>>(rel_bf, WihT, gru_bih, GI);
  for (int s=0; s<SEQQ; ++s){
    if (s > 0)
      k_gemm<<<dim3(32,6),256,0,stream>>>(hbf, WhhT, gru_bhh, gh);
    k_update<<<4096,256,0,stream>>>(GI, gh, gru_bhh, time_idx, h, h, hbf, out, s);
  }
}